// Round 16
// baseline (5831.843 us; speedup 1.0000x reference)
//
#include <hip/hip_runtime.h>
#include <math.h>

#define NB 16
#define NT 512
#define NE 1024
#define ND 1024
#define NA 1024
#define NO 10000
#define NL 128
#define NOL 129
#define NROWS (NB*NOL)   /* 2064 */
#define TOK_SOS 9999
#define TOK_EOS 9999
#define NBLK 256

typedef unsigned short u16;
typedef unsigned int u32;
typedef __bf16 bf16x8 __attribute__((ext_vector_type(8)));
typedef float f32x4 __attribute__((ext_vector_type(4)));
typedef unsigned short u16x8 __attribute__((ext_vector_type(8)));
typedef unsigned short u16x4 __attribute__((ext_vector_type(4)));

__device__ __forceinline__ float sigf(float x){ return 1.0f/(1.0f+expf(-x)); }
__device__ __forceinline__ float b2f(u16 s){
  union { u32 i; float f; } u; u.i = ((u32)s) << 16; return u.f;
}
__device__ __forceinline__ u16 f2b(float f){
  union { float f; u32 i; } u; u.f = f;
  u32 r = u.i + 0x7FFFu + ((u.i >> 16) & 1u);
  return (u16)(r >> 16);
}
__device__ __forceinline__ float dot8(bf16x8 a, bf16x8 b){
  float s = 0.f;
  #pragma unroll
  for (int j=0;j<8;++j) s += (float)a[j]*(float)b[j];
  return s;
}

// ---- producer write-through stores / flag ops (agent-relaxed, proven) ----
__device__ __forceinline__ void coh_stf(float* p, float v){
  __hip_atomic_store(p, v, __ATOMIC_RELAXED, __HIP_MEMORY_SCOPE_AGENT);
}
__device__ __forceinline__ u32 coh_ldu(const u32* p){
  return __hip_atomic_load((u32*)p, __ATOMIC_RELAXED, __HIP_MEMORY_SCOPE_AGENT);
}
__device__ __forceinline__ void coh_stu(u32* p, u32 v){
  __hip_atomic_store(p, v, __ATOMIC_RELAXED, __HIP_MEMORY_SCOPE_AGENT);
}

// ---------------- zero ----------------
__global__ void zero4_kernel(uint4* __restrict__ p, int n){
  int i = blockIdx.x*256 + threadIdx.x;
  if (i < n) p[i] = make_uint4(0,0,0,0);
}

// ---------------- fused f32 -> bf16 gate-weight conversions (5 configs) ----------------
__global__ __launch_bounds__(256) void cvt5_kernel(
    const float* __restrict__ Wih0, const float* __restrict__ Whh0,
    const float* __restrict__ Wih1, const float* __restrict__ Whh1,
    u16* __restrict__ w0c, u16* __restrict__ wh0,
    u16* __restrict__ w1c, u16* __restrict__ wh1, u16* __restrict__ w0e){
  const float* src; int ld, off; u16* dst;
  switch (blockIdx.y){
    case 0:  src = Wih0; ld = 2048; off = 1024; dst = w0c; break;
    case 1:  src = Whh0; ld = 1024; off = 0;    dst = wh0; break;
    case 2:  src = Wih1; ld = 1024; off = 0;    dst = w1c; break;
    case 3:  src = Whh1; ld = 1024; off = 0;    dst = wh1; break;
    default: src = Wih0; ld = 2048; off = 0;    dst = w0e; break;
  }
  int i = (blockIdx.x*256 + threadIdx.x)*4;
  int row = i >> 10, col = i & 1023;
  float4 v = *(const float4*)(src + (size_t)row*ld + off + col);
  u16x4 o = { f2b(v.x), f2b(v.y), f2b(v.z), f2b(v.w) };
  *(u16x4*)(dst + i) = o;
}

// ---------------- transpose-convert: src f32 [R][C] -> dst bf16 [C'][R] ----------------
__global__ __launch_bounds__(256) void tcvt_kernel(
    const float* __restrict__ src, int R, int C, u16* __restrict__ dst){
  __shared__ float tile[32][33];
  const int c0 = blockIdx.x*32, r0 = blockIdx.y*32;
  const int tx = threadIdx.x & 31, ty = threadIdx.x >> 5;
  #pragma unroll
  for (int k = 0; k < 4; ++k){
    int rr = ty + k*8;
    int c = c0 + tx;
    float v = (c < C) ? src[(size_t)(r0+rr)*C + c] : 0.0f;
    tile[rr][tx] = v;
  }
  __syncthreads();
  #pragma unroll
  for (int k = 0; k < 4; ++k){
    int cc = ty + k*8;
    dst[(size_t)(c0+cc)*R + r0 + tx] = f2b(tile[tx][cc]);
  }
}

// ---------------- hpad masked f32 -> bf16 [16][512][1024] ----------------
__global__ __launch_bounds__(256) void hpadbf_kernel(
    const float* __restrict__ hpad, const int* __restrict__ hlen, u16* __restrict__ dst){
  int i = (blockIdx.x*256 + threadIdx.x)*4;
  int bt = i >> 10;
  int b = bt >> 9, tt = bt & 511;
  float4 v = *(const float4*)(hpad + (size_t)i);
  float m = (tt < hlen[b]) ? 1.0f : 0.0f;
  u16x4 o = { f2b(v.x*m), f2b(v.y*m), f2b(v.z*m), f2b(v.w*m) };
  *(u16x4*)(dst + i) = o;
}

// ---------------- hpad [16][512][1024] f32 -> masked bf16 transposed [16][1024][512] -------
__global__ __launch_bounds__(256) void hpadT_kernel(
    const float* __restrict__ hpad, const int* __restrict__ hlen, u16* __restrict__ dst){
  __shared__ float tile[32][33];
  const int e0 = blockIdx.x*32, t0 = blockIdx.y*32, b = blockIdx.z;
  const int tx = threadIdx.x & 31, ty = threadIdx.x >> 5;
  const int len = hlen[b];
  #pragma unroll
  for (int k = 0; k < 4; ++k){
    int r = ty + k*8;
    tile[r][tx] = hpad[((size_t)b*512 + t0 + r)*1024 + e0 + tx];
  }
  __syncthreads();
  #pragma unroll
  for (int k = 0; k < 4; ++k){
    int el = ty + k*8;
    float m = (t0 + tx < len) ? 1.0f : 0.0f;
    dst[((size_t)b*1024 + e0 + el)*512 + t0 + tx] = f2b(tile[tx][el]*m);
  }
}

// ---------------- bias1 = bih1 + bhh1 ----------------
__global__ void bias_add_kernel(const float* __restrict__ a, const float* __restrict__ b,
                                float* __restrict__ o){
  int i = blockIdx.x*256 + threadIdx.x;
  if (i < 4096) o[i] = a[i] + b[i];
}

// ---------------- eys = bf16(embed[ys_in]) [2176][1024] (rows >= 2064 zeroed) --------------
__global__ __launch_bounds__(256) void eys_kernel(
    const int* __restrict__ ys, const float* __restrict__ embed, u16* __restrict__ eys){
  int row = blockIdx.x;
  int c = threadIdx.x*4;
  if (row < NROWS){
    int b = row / NOL, l = row - b*NOL;
    int tok = (l==0) ? TOK_SOS : ys[b*NL + l - 1];
    float4 v = *(const float4*)(embed + (size_t)tok*1024 + c);
    u16x4 o = { f2b(v.x), f2b(v.y), f2b(v.z), f2b(v.w) };
    *(u16x4*)(eys + (size_t)row*1024 + c) = o;
  } else {
    u16x4 o = {0,0,0,0};
    *(u16x4*)(eys + (size_t)row*1024 + c) = o;
  }
}

// ---------------- generic 128x128 bf16 MFMA tile body ----------------
#define GEMM128_BODY(Aptr, Bptr) \
  const int tid = threadIdx.x, lane = tid & 63, wv = tid >> 6; \
  const int r = lane & 15, q = lane >> 4; \
  const int m0 = blockIdx.x*128, n0 = blockIdx.y*128; \
  const int ar0 = m0 + wv*32 + r; \
  f32x4 acc[2][8]; \
  _Pragma("unroll") \
  for (int a = 0; a < 2; ++a) \
    _Pragma("unroll") \
    for (int s = 0; s < 8; ++s) acc[a][s] = (f32x4){0.f,0.f,0.f,0.f}; \
  const u16* a0p = (Aptr) + (size_t)ar0*1024 + q*8; \
  const u16* a1p = a0p + 16*1024; \
  const u16* bp  = (Bptr) + (size_t)(n0 + r)*1024 + q*8; \
  for (int kt = 0; kt < 32; ++kt){ \
    bf16x8 av0 = *(const bf16x8*)(a0p + kt*32); \
    bf16x8 av1 = *(const bf16x8*)(a1p + kt*32); \
    _Pragma("unroll") \
    for (int s = 0; s < 8; ++s){ \
      bf16x8 bv = *(const bf16x8*)(bp + (size_t)s*16384 + kt*32); \
      acc[0][s] = __builtin_amdgcn_mfma_f32_16x16x32_bf16(av0, bv, acc[0][s], 0,0,0); \
      acc[1][s] = __builtin_amdgcn_mfma_f32_16x16x32_bf16(av1, bv, acc[1][s], 0,0,0); \
    } \
  }

__global__ __launch_bounds__(256) void preenc_g(
    const u16* __restrict__ hpadbf, const u16* __restrict__ wencT, u16* __restrict__ pre){
  GEMM128_BODY(hpadbf, wencT)
  #pragma unroll
  for (int a = 0; a < 2; ++a)
    #pragma unroll
    for (int s = 0; s < 8; ++s)
      #pragma unroll
      for (int rr = 0; rr < 4; ++rr){
        int row = m0 + wv*32 + a*16 + q*4 + rr, col = n0 + s*16 + r;
        pre[(size_t)row*1024 + col] = f2b(tanhf(acc[a][s][rr]));
      }
}

__global__ __launch_bounds__(256) void gey_g(
    const u16* __restrict__ eys, const u16* __restrict__ w0e,
    const float* __restrict__ bih0, const float* __restrict__ bhh0, u16* __restrict__ gey){
  GEMM128_BODY(eys, w0e)
  #pragma unroll
  for (int a = 0; a < 2; ++a)
    #pragma unroll
    for (int s = 0; s < 8; ++s)
      #pragma unroll
      for (int rr = 0; rr < 4; ++rr){
        int row = m0 + wv*32 + a*16 + q*4 + rr, col = n0 + s*16 + r;
        if (row < NROWS)
          gey[(size_t)row*4096 + col] = f2b(acc[a][s][rr] + bih0[col] + bhh0[col]);
      }
}

__global__ __launch_bounds__(256) void logits_g(
    const u16* __restrict__ zallb, const u16* __restrict__ woutT,
    const float* __restrict__ bout, u16* __restrict__ logits){
  GEMM128_BODY(zallb, woutT)
  #pragma unroll
  for (int a = 0; a < 2; ++a)
    #pragma unroll
    for (int s = 0; s < 8; ++s)
      #pragma unroll
      for (int rr = 0; rr < 4; ++rr){
        int row = m0 + wv*32 + a*16 + q*4 + rr, col = n0 + s*16 + r;
        if (row < NROWS && col < NO)
          logits[(size_t)row*NO + col] = f2b(acc[a][s][rr] + bout[col]);
      }
}

// ---------------- split grid barrier: arrive / mid (leader release) / fin ----------------
// arrive: drain phase stores, post flag. mid: leader gathers flags and releases go
// IMMEDIATELY (before its own hoisted work). fin: observers check go. Hoisted
// barrier-independent compute goes between mid and fin.
__device__ __forceinline__ void bar_arrive(u32* af, int e){
  __syncthreads();
  if (blockIdx.x != 0 && threadIdx.x == 0) coh_stu(&af[blockIdx.x << 5], (u32)e);
}
__device__ __forceinline__ void bar_mid(u32* af, int e){
  if (blockIdx.x == 0){
    int w = threadIdx.x;
    if (w > 0){
      while ((int)coh_ldu(&af[w << 5]) < e) __builtin_amdgcn_s_sleep(1);
    }
    __syncthreads();
    if (threadIdx.x == 0) coh_stu(&af[0], (u32)e);
  }
}
__device__ __forceinline__ void bar_fin(u32* af, int e){
  if (blockIdx.x != 0){
    if (threadIdx.x == 0){
      while ((int)coh_ldu(&af[0]) < e) __builtin_amdgcn_s_sleep(1);
    }
  }
  __syncthreads();
}
__device__ __forceinline__ void gbar(u32* af, int e){
  bar_arrive(af, e); bar_mid(af, e); bar_fin(af, e);
}

// ---------------- 16-WG group barrier (one hop: store + 16 parallel polls) ----------------
__device__ __forceinline__ void group_bar(u32* gfl, int epoch){
  __syncthreads();
  if (threadIdx.x == 0) coh_stu(&gfl[blockIdx.x << 5], (u32)epoch);
  const int base = blockIdx.x & ~15;
  if ((int)threadIdx.x < 16){
    while ((int)coh_ldu(&gfl[(base + threadIdx.x) << 5]) < epoch) __builtin_amdgcn_s_sleep(1);
  }
  __syncthreads();
}

// one 16x16 output tile, K=512 slice per wave; weights from LDS, A cached from ring
__device__ __forceinline__ f32x4 tile_gemm(const u16* lw, const u16* ab){
  f32x4 acc = {0.f,0.f,0.f,0.f};
  #pragma unroll
  for (int kt = 0; kt < 16; ++kt){
    bf16x8 a = *(const bf16x8*)(ab + kt*32);
    bf16x8 b = *(const bf16x8*)(lw + kt*512);
    acc = __builtin_amdgcn_mfma_f32_16x16x32_bf16(a, b, acc, 0, 0, 0);
  }
  return acc;
}

// ---------------- persistent sequential kernel: rings + split barriers ----------------
__global__ __launch_bounds__(256, 1) void seq_kernel(
    const u16* __restrict__ pre,    // [8192][1024] bf16 (cached)
    const u16* __restrict__ hpadT,  // [16][1024][512] bf16 masked (cached)
    const u16* __restrict__ w0c, const u16* __restrict__ wh0,
    const u16* __restrict__ w1c, const u16* __restrict__ wh1,
    const u16* __restrict__ wdecT,  // [1024 n][1024 k] bf16 (cached)
    const u16* __restrict__ gey,    // [2064][4096] bf16 (cached)
    const float* __restrict__ bias1,// [4096]
    const int* __restrict__ hlen,
    u16* dqr,                       // ring [129][16][1024] bf16
    float* escr,                    // ring [129][16][512] f32
    u16* attcr,                     // ring [129][16][1024] bf16
    u16* z0r,                       // ring [130][16][1024] bf16 (slot0 zeroed)
    u16* z1r,                       // ring [130][16][1024] bf16 (slot0 zeroed)
    u16* zallb,                     // [2176][1024] bf16 (normal stores)
    u32* af, u32* gfl)
{
  __builtin_amdgcn_fence(__ATOMIC_ACQUIRE, "agent");

  const int wg = blockIdx.x, tid = threadIdx.x;
  const int lane = tid & 63, wv = tid >> 6;
  const int r = lane & 15, q = lane >> 4;

  extern __shared__ __align__(16) u16 dynlds[];
  u16* lw1 = dynlds;            // 64 KB (layer1 gates)
  u16* lw0 = dynlds + 32768;    // 64 KB (layer0 gates)
  __shared__ float sred8[8];
  __shared__ float sw[512];
  __shared__ float spart[4][64];
  __shared__ float gex[4][16][16];
  __shared__ float sdq[16*16*4];

  const int dg16 = (wg & 63)*16, sub4 = (wg >> 6)*4;

  #pragma unroll
  for (int it = 0; it < 16; ++it){
    int m = tid + it*256;
    int kb = m >> 4, c = m & 15;
    int k0 = kb*8;
    int gi = c >> 2;
    int d  = dg16 + sub4 + (c & 3);
    size_t gr = (size_t)(gi*1024 + d)*1024;
    const u16* s1 = (k0 < 1024) ? (w1c + gr + k0) : (wh1 + gr + k0 - 1024);
    const u16* s0 = (k0 < 1024) ? (w0c + gr + k0) : (wh0 + gr + k0 - 1024);
    *(u16x8*)(lw1 + (m << 3)) = *(const u16x8*)s1;
    *(u16x8*)(lw0 + (m << 3)) = *(const u16x8*)s0;
  }
  __syncthreads();

  float c0r = 0.f, c1r = 0.f;
  const int lwoff = ((wv*64 + q)*16 + r) << 3;

  for (int t = 0; t <= NOL; ++t){
    const u16* z0t = z0r + (size_t)t*16384;
    u16* dq_t   = dqr   + (size_t)t*16384;
    float* esc_t= escr  + (size_t)t*8192;
    u16* attc_t = attcr + (size_t)t*16384;

    // ======== Phase A: gemm1+cell1(t-1), dq(t) ========
    // z1-half of gemm1 is independent of the pending D-barrier -> hoist before fin
    f32x4 accA = {0.f,0.f,0.f,0.f};
    if (t >= 1 && wv >= 2){
      const u16* z1p = z1r + (size_t)(t-1)*16384;
      const u16* ab = z1p + r*1024 + (wv & 1)*512 + q*8;
      accA = tile_gemm(lw1 + lwoff, ab);
    }
    if (t > 0) bar_fin(af, 3*t);        // completes D-barrier of iteration t-1
    if (t >= 1){
      const int s = t - 1;
      if (wv < 2){
        const u16* ab = z0t + r*1024 + (wv & 1)*512 + q*8;
        accA = tile_gemm(lw1 + lwoff, ab);
      }
      #pragma unroll
      for (int rr = 0; rr < 4; ++rr) gex[wv][q*4+rr][r] = accA[rr];
      __syncthreads();
      if (tid < 64){
        int b = tid >> 2, dd = tid & 3, d = dg16 + sub4 + dd;
        float g0 = gex[0][b][0*4+dd] + gex[1][b][0*4+dd] + gex[2][b][0*4+dd] + gex[3][b][0*4+dd];
        float g1 = gex[0][b][1*4+dd] + gex[1][b][1*4+dd] + gex[2][b][1*4+dd] + gex[3][b][1*4+dd];
        float g2 = gex[0][b][2*4+dd] + gex[1][b][2*4+dd] + gex[2][b][2*4+dd] + gex[3][b][2*4+dd];
        float g3 = gex[0][b][3*4+dd] + gex[1][b][3*4+dd] + gex[2][b][3*4+dd] + gex[3][b][3*4+dd];
        g0 += bias1[d]; g1 += bias1[1024+d]; g2 += bias1[2048+d]; g3 += bias1[3072+d];
        float cn = sigf(g1)*c1r + sigf(g0)*tanhf(g2);
        float zn = sigf(g3)*tanhf(cn);
        c1r = cn;
        float zn2 = __shfl_down(zn, 1);
        if ((tid & 1) == 0){
          u32 pk = (u32)f2b(zn) | ((u32)f2b(zn2) << 16);
          *(u32*)(zallb + ((size_t)b*NOL + s)*1024 + d) = pk;
          coh_stu((u32*)(z1r + (size_t)t*16384 + b*1024 + d), pk);
        }
      }
      __syncthreads();
    }
    if (t == NOL) break;                 // final gemm1 done; kernel-end flush covers stores
    {
      const int b = tid & 15, ks = tid >> 4;
      float a4[4] = {0.f,0.f,0.f,0.f};
      #pragma unroll
      for (int i = 0; i < 8; ++i){
        bf16x8 za = *(const bf16x8*)(z0t + b*1024 + ks*64 + i*8);
        #pragma unroll
        for (int nn = 0; nn < 4; ++nn){
          bf16x8 wb = *(const bf16x8*)(wdecT + (size_t)(wg*4+nn)*1024 + ks*64 + i*8);
          a4[nn] += dot8(za, wb);
        }
      }
      #pragma unroll
      for (int nn = 0; nn < 4; ++nn) sdq[(ks*16 + b)*4 + nn] = a4[nn];
      __syncthreads();
      if (tid < 64){
        int b2 = tid >> 2, nn = tid & 3;
        float s2 = 0.f;
        #pragma unroll
        for (int ks2 = 0; ks2 < 16; ++ks2) s2 += sdq[(ks2*16 + b2)*4 + nn];
        float dv = tanhf(s2);
        float dv2 = __shfl_down(dv, 1);
        if ((tid & 1) == 0){
          u32 pk = (u32)f2b(dv) | ((u32)f2b(dv2) << 16);
          coh_stu((u32*)(dq_t + b2*1024 + wg*4 + nn), pk);
        }
      }
    }
    gbar(af, 3*t + 1);

    // ======== Phase B: escore = 2 * pre . dq  (32 rows per WG) ========
    {
      const int rbase = wg*32 + wv*8;
      const int b = (wg*32) >> 9;
      const u16* dqb = dq_t + b*1024 + lane*16;
      u16x8 d0 = *(const u16x8*)(dqb);
      u16x8 d1 = *(const u16x8*)(dqb + 8);
      float qv[16];
      #pragma unroll
      for (int j = 0; j < 8; ++j){ qv[j] = b2f(d0[j]); qv[8+j] = b2f(d1[j]); }
      #pragma unroll
      for (int rr = 0; rr < 8; ++rr){
        const u16* pr = pre + (size_t)(rbase+rr)*1024 + lane*16;
        u16x8 p0 = *(const u16x8*)(pr);
        u16x8 p1 = *(const u16x8*)(pr+8);
        float acc = 0.f;
        #pragma unroll
        for (int j = 0; j < 8; ++j){
          acc += b2f(p0[j])*qv[j];
          acc += b2f(p1[j])*qv[8+j];
        }
        #pragma unroll
        for (int off = 32; off > 0; off >>= 1) acc += __shfl_xor(acc, off, 64);
        if (lane == 0) coh_stf(&esc_t[rbase+rr], 2.0f*acc);
      }
    }
    group_bar(gfl, t + 1);

    // ======== Phase C: softmax + att_c (b = wg>>4, 64-col e-slice; wave reductions) =======
    {
      const int b = wg >> 4, ec = wg & 15;
      const int len = hlen[b];
      float e0 = (tid < len)     ? esc_t[b*512 + tid]       : -INFINITY;
      float e1 = (tid+256 < len) ? esc_t[b*512 + tid + 256] : -INFINITY;
      float mloc = fmaxf(e0, e1);
      #pragma unroll
      for (int off = 32; off > 0; off >>= 1) mloc = fmaxf(mloc, __shfl_xor(mloc, off, 64));
      if (lane == 0) sred8[wv] = mloc;
      __syncthreads();
      float mx = fmaxf(fmaxf(sred8[0], sred8[1]), fmaxf(sred8[2], sred8[3]));
      float p0 = (tid < len)     ? expf(e0 - mx) : 0.0f;
      float p1 = (tid+256 < len) ? expf(e1 - mx) : 0.0f;
      float sloc = p0 + p1;
      #pragma unroll
      for (int off = 32; off > 0; off >>= 1) sloc += __shfl_xor(sloc, off, 64);
      if (lane == 0) sred8[4 + wv] = sloc;
      __syncthreads();
      float inv = 1.0f/(sred8[4] + sred8[5] + sred8[6] + sred8[7]);
      sw[tid] = p0*inv; sw[tid+256] = p1*inv;
      __syncthreads();
      const int el = tid & 63, th = tid >> 6;
      const u16* hp = hpadT + ((size_t)b*1024 + ec*64 + el)*512 + th*128;
      float acc = 0.f;
      #pragma unroll
      for (int i = 0; i < 16; ++i){
        u16x8 v = *(const u16x8*)(hp + i*8);
        #pragma unroll
        for (int j = 0; j < 8; ++j) acc += sw[th*128 + i*8 + j]*b2f(v[j]);
      }
      spart[th][el] = acc;
      __syncthreads();
      if (tid < 64){
        float s2 = spart[0][tid]+spart[1][tid]+spart[2][tid]+spart[3][tid];
        float s2n = __shfl_down(s2, 1);
        if ((tid & 1) == 0){
          u32 pk = (u32)f2b(s2) | ((u32)f2b(s2n) << 16);
          coh_stu((u32*)(attc_t + b*1024 + ec*64 + tid), pk);
        }
      }
    }
    // ======== C->D barrier split: hoist z0-half of gemm0 between release and wait ========
    bar_arrive(af, 3*t + 2);
    bar_mid(af, 3*t + 2);
    f32x4 accD = {0.f,0.f,0.f,0.f};
    if (wv >= 2){
      const u16* ab = z0t + r*1024 + (wv & 1)*512 + q*8;
      accD = tile_gemm(lw0 + lwoff, ab);
    }
    bar_fin(af, 3*t + 2);

    // ======== Phase D: gemm0 + cell0(t) -> z0 ring slot t+1 ========
    {
      if (wv < 2){
        const u16* ab = attc_t + r*1024 + (wv & 1)*512 + q*8;
        accD = tile_gemm(lw0 + lwoff, ab);
      }
      #pragma unroll
      for (int rr = 0; rr < 4; ++rr) gex[wv][q*4+rr][r] = accD[rr];
      __syncthreads();
      if (tid < 64){
        int b = tid >> 2, dd = tid & 3, d = dg16 + sub4 + dd;
        const u16* gr = gey + ((size_t)b*NOL + t)*4096 + d;
        float g0 = gex[0][b][0*4+dd] + gex[1][b][0*4+dd] + gex[2][b][0*4+dd] + gex[3][b][0*4+dd];
        float g1 = gex[0][b][1*4+dd] + gex[1][b][1*4+dd] + gex[2][b][1*4+dd] + gex[3][b][1*4+dd];
        float g2 = gex[0][b][2*4+dd] + gex[1][b][2*4+dd] + gex[2][b][2*4+dd] + gex[3][b][2*4+dd];
        float g3 = gex[0][b][3*4+dd] + gex[1][b][3*4+dd] + gex[2][b][3*4+dd] + gex[3][b][3*4+dd];
        g0 += b2f(gr[0]); g1 += b2f(gr[1024]); g2 += b2f(gr[2048]); g3 += b2f(gr[3072]);
        float cn = sigf(g1)*c0r + sigf(g0)*tanhf(g2);
        float zn = sigf(g3)*tanhf(cn);
        c0r = cn;
        float zn2 = __shfl_down(zn, 1);
        if ((tid & 1) == 0){
          u32 pk = (u32)f2b(zn) | ((u32)f2b(zn2) << 16);
          coh_stu((u32*)(z0r + (size_t)(t+1)*16384 + b*1024 + d), pk);
        }
      }
    }
    // D->A barrier split: arrive+release now; next iteration hoists z1-half before fin
    bar_arrive(af, 3*t + 3);
    bar_mid(af, 3*t + 3);
  }
}

// ---------------- per-row single-pass online log_softmax + NLL + argmax ----------------
__global__ __launch_bounds__(256) void loss_kernel(
    const u16* __restrict__ logits, const int* __restrict__ ys, float* __restrict__ accum){
  int row = blockIdx.x;
  int tid = threadIdx.x;
  const u16* lr = logits + (size_t)row * NO;
  __shared__ float sm[256], ss[256];
  __shared__ int   si[256];
  float m = -INFINITY, s = 0.f; int mi = 0x7FFFFFFF;
  for (int n = tid; n < NO; n += 256){
    float v = b2f(lr[n]);
    if (v > m){
      s = s*__expf(m - v) + 1.0f;
      m = v; mi = n;
    } else {
      s += __expf(v - m);
    }
  }
  sm[tid] = m; ss[tid] = s; si[tid] = mi;
  __syncthreads();
  for (int st = 128; st > 0; st >>= 1){
    if (tid < st){
      float m1 = sm[tid], s1 = ss[tid]; int i1 = si[tid];
      float m2 = sm[tid+st], s2 = ss[tid+st]; int i2 = si[tid+st];
      float M = fmaxf(m1, m2);
      ss[tid] = s1*__expf(m1 - M) + s2*__expf(m2 - M);
      sm[tid] = M;
      si[tid] = (m1 > m2) ? i1 : (m2 > m1) ? i2 : min(i1, i2);
    }
    __syncthreads();
  }
  if (tid == 0){
    int b = row / NOL, l = row - b*NOL;
    int label = (l < NL) ? ys[b*NL + l] : TOK_EOS;
    float lse = sm[0] + logf(ss[0]);
    float nll = lse - b2f(lr[label]);
    atomicAdd(&accum[0], nll);
    atomicAdd(&accum[1], (si[0]==label) ? 1.0f : 0.0f);
  }
}

__global__ void finalize_kernel(const float* __restrict__ accum, float* __restrict__ out){
  out[0] = accum[0] / (float)NROWS * (float)(NOL-1);
  out[1] = accum[1] / (float)NROWS;
}

extern "C" void kernel_launch(void* const* d_in, const int* in_sizes, int n_in,
                              void* d_out, int out_size, void* d_ws, size_t ws_size,
                              hipStream_t stream){
  const float* hpad  = (const float*)d_in[0];
  const int*   hlen  = (const int*)  d_in[1];
  const int*   ys    = (const int*)  d_in[2];
  const float* embed = (const float*)d_in[3];
  const float* Wenc  = (const float*)d_in[4];
  const float* Wdec  = (const float*)d_in[5];
  const float* Wih0  = (const float*)d_in[6];
  const float* Whh0  = (const float*)d_in[7];
  const float* bih0  = (const float*)d_in[8];
  const float* bhh0  = (const float*)d_in[9];
  const float* Wih1  = (const float*)d_in[10];
  const float* Whh1  = (const float*)d_in[11];
  const float* bih1  = (const float*)d_in[12];
  const float* bhh1  = (const float*)d_in[13];
  const float* Wout  = (const float*)d_in[14];
  const float* bout  = (const float*)d_in[15];
  float* out = (float*)d_out;

  char* ws = (char*)d_ws;
  size_t cur = 0;
  auto alloc = [&](size_t bytes) -> char* {
    char* p = ws + cur;
    cur += (bytes + 255) & ~(size_t)255;
    return p;
  };
  u16*   pre_bf   = (u16*)  alloc(16777216);   // [8192][1024]
  u16*   hpadT    = (u16*)  alloc(16777216);   // [16][1024][512]
  u16*   w0c      = (u16*)  alloc(8388608);    // Wih0[:,1024:]
  u16*   wh0      = (u16*)  alloc(8388608);
  u16*   w1c      = (u16*)  alloc(8388608);
  u16*   wh1      = (u16*)  alloc(8388608);
  u16*   wdecT    = (u16*)  alloc(2097152);    // [1024][1024]
  u16*   wencT    = (u16*)  alloc(2097152);    // [1024][1024]
  u16*   woutT    = (u16*)  alloc(20709376);   // [10112][1024]
  u16*   gey      = (u16*)  alloc(16908288);   // [2064][4096]
  u16*   zallb    = (u16*)  alloc(4456448);    // [2176][1024]
  u16*   logits   = (u16*)  alloc(41280000);   // [2064][10000]
  float* bias1    = (float*)alloc(16384);
  // ---- write-once rings ----
  u16*   dqr      = (u16*)  alloc(129u*32768);
  float* escr     = (float*)alloc(129u*32768);
  u16*   attcr    = (u16*)  alloc(129u*32768);
  u16*   z0r      = (u16*)  alloc(130u*32768);
  u16*   z1r      = (u16*)  alloc(130u*32768);
  // ---- zeroed each launch ----
  u32*   af       = (u32*)  alloc(32768);
  u32*   gfl      = (u32*)  alloc(32768);
  float* accum    = (float*)alloc(128);

  // pre-seq staging buffers ALIAS the logits region (dead until logits_g)
  u16*   hpad_bf  = (u16*)logits;              // 16 MB
  u16*   eys      = (u16*)(logits + 8388608);
  u16*   w0e      = (u16*)(logits + 11165696);

  zero4_kernel<<<17, 256, 0, stream>>>((uint4*)af, 4104);
  zero4_kernel<<<8, 256, 0, stream>>>((uint4*)z0r, 2048);
  zero4_kernel<<<8, 256, 0, stream>>>((uint4*)z1r, 2048);

  tcvt_kernel<<<dim3(32,32),  256, 0, stream>>>(Wenc, 1024, 1024, wencT);
  tcvt_kernel<<<dim3(32,32),  256, 0, stream>>>(Wdec, 1024, 1024, wdecT);
  tcvt_kernel<<<dim3(316,32), 256, 0, stream>>>(Wout, 1024, NO,   woutT);
  cvt5_kernel<<<dim3(4096,5), 256, 0, stream>>>(Wih0, Whh0, Wih1, Whh1,
                                                w0c, wh0, w1c, wh1, w0e);
  hpadbf_kernel<<<8192, 256, 0, stream>>>(hpad, hlen, hpad_bf);
  hpadT_kernel<<<dim3(32,16,16), 256, 0, stream>>>(hpad, hlen, hpadT);
  bias_add_kernel<<<16, 256, 0, stream>>>(bih1, bhh1, bias1);
  eys_kernel<<<2176, 256, 0, stream>>>(ys, embed, eys);

  preenc_g<<<dim3(64, 8),  256, 0, stream>>>(hpad_bf, wencT, pre_bf);
  gey_g   <<<dim3(17, 32), 256, 0, stream>>>(eys, w0e, bih0, bhh0, gey);

  hipFuncSetAttribute((const void*)seq_kernel,
                      hipFuncAttributeMaxDynamicSharedMemorySize, 131072);
  seq_kernel<<<NBLK, 256, 131072, stream>>>(pre_bf, hpadT, w0c, wh0, w1c, wh1,
                                            wdecT, gey, bias1, hlen,
                                            dqr, escr, attcr, z0r, z1r, zallb, af, gfl);

  logits_g<<<dim3(17, 79), 256, 0, stream>>>(zallb, woutT, bout, logits);
  loss_kernel<<<NROWS, 256, 0, stream>>>(logits, ys, accum);
  finalize_kernel<<<1, 1, 0, stream>>>(accum, out);
}

// Round 17
// 3509.057 us; speedup vs baseline: 1.6619x; 1.6619x over previous
//
#include <hip/hip_runtime.h>
#include <math.h>

#define NB 16
#define NT 512
#define NE 1024
#define ND 1024
#define NA 1024
#define NO 10000
#define NL 128
#define NOL 129
#define NROWS (NB*NOL)   /* 2064 */
#define TOK_SOS 9999
#define TOK_EOS 9999
#define NBLK 256

typedef unsigned short u16;
typedef unsigned int u32;
typedef __bf16 bf16x8 __attribute__((ext_vector_type(8)));
typedef float f32x4 __attribute__((ext_vector_type(4)));
typedef unsigned short u16x8 __attribute__((ext_vector_type(8)));
typedef unsigned short u16x4 __attribute__((ext_vector_type(4)));

__device__ __forceinline__ float sigf(float x){ return 1.0f/(1.0f+expf(-x)); }
__device__ __forceinline__ float b2f(u16 s){
  union { u32 i; float f; } u; u.i = ((u32)s) << 16; return u.f;
}
__device__ __forceinline__ u16 f2b(float f){
  union { float f; u32 i; } u; u.f = f;
  u32 r = u.i + 0x7FFFu + ((u.i >> 16) & 1u);
  return (u16)(r >> 16);
}
__device__ __forceinline__ float dot8(bf16x8 a, bf16x8 b){
  float s = 0.f;
  #pragma unroll
  for (int j=0;j<8;++j) s += (float)a[j]*(float)b[j];
  return s;
}

// ---- producer write-through stores / flag ops (agent-relaxed, proven) ----
__device__ __forceinline__ void coh_stf(float* p, float v){
  __hip_atomic_store(p, v, __ATOMIC_RELAXED, __HIP_MEMORY_SCOPE_AGENT);
}
__device__ __forceinline__ u32 coh_ldu(const u32* p){
  return __hip_atomic_load((u32*)p, __ATOMIC_RELAXED, __HIP_MEMORY_SCOPE_AGENT);
}
__device__ __forceinline__ void coh_stu(u32* p, u32 v){
  __hip_atomic_store(p, v, __ATOMIC_RELAXED, __HIP_MEMORY_SCOPE_AGENT);
}

// ---------------- zero ----------------
__global__ void zero4_kernel(uint4* __restrict__ p, int n){
  int i = blockIdx.x*256 + threadIdx.x;
  if (i < n) p[i] = make_uint4(0,0,0,0);
}

// ---------------- fused f32 -> bf16 gate-weight conversions (5 configs) ----------------
__global__ __launch_bounds__(256) void cvt5_kernel(
    const float* __restrict__ Wih0, const float* __restrict__ Whh0,
    const float* __restrict__ Wih1, const float* __restrict__ Whh1,
    u16* __restrict__ w0c, u16* __restrict__ wh0,
    u16* __restrict__ w1c, u16* __restrict__ wh1, u16* __restrict__ w0e){
  const float* src; int ld, off; u16* dst;
  switch (blockIdx.y){
    case 0:  src = Wih0; ld = 2048; off = 1024; dst = w0c; break;
    case 1:  src = Whh0; ld = 1024; off = 0;    dst = wh0; break;
    case 2:  src = Wih1; ld = 1024; off = 0;    dst = w1c; break;
    case 3:  src = Whh1; ld = 1024; off = 0;    dst = wh1; break;
    default: src = Wih0; ld = 2048; off = 0;    dst = w0e; break;
  }
  int i = (blockIdx.x*256 + threadIdx.x)*4;
  int row = i >> 10, col = i & 1023;
  float4 v = *(const float4*)(src + (size_t)row*ld + off + col);
  u16x4 o = { f2b(v.x), f2b(v.y), f2b(v.z), f2b(v.w) };
  *(u16x4*)(dst + i) = o;
}

// ---------------- transpose-convert: src f32 [R][C] -> dst bf16 [C'][R] ----------------
__global__ __launch_bounds__(256) void tcvt_kernel(
    const float* __restrict__ src, int R, int C, u16* __restrict__ dst){
  __shared__ float tile[32][33];
  const int c0 = blockIdx.x*32, r0 = blockIdx.y*32;
  const int tx = threadIdx.x & 31, ty = threadIdx.x >> 5;
  #pragma unroll
  for (int k = 0; k < 4; ++k){
    int rr = ty + k*8;
    int c = c0 + tx;
    float v = (c < C) ? src[(size_t)(r0+rr)*C + c] : 0.0f;
    tile[rr][tx] = v;
  }
  __syncthreads();
  #pragma unroll
  for (int k = 0; k < 4; ++k){
    int cc = ty + k*8;
    dst[(size_t)(c0+cc)*R + r0 + tx] = f2b(tile[tx][cc]);
  }
}

// ---------------- hpad masked f32 -> bf16 [16][512][1024] ----------------
__global__ __launch_bounds__(256) void hpadbf_kernel(
    const float* __restrict__ hpad, const int* __restrict__ hlen, u16* __restrict__ dst){
  int i = (blockIdx.x*256 + threadIdx.x)*4;
  int bt = i >> 10;
  int b = bt >> 9, tt = bt & 511;
  float4 v = *(const float4*)(hpad + (size_t)i);
  float m = (tt < hlen[b]) ? 1.0f : 0.0f;
  u16x4 o = { f2b(v.x*m), f2b(v.y*m), f2b(v.z*m), f2b(v.w*m) };
  *(u16x4*)(dst + i) = o;
}

// ---------------- hpad [16][512][1024] f32 -> masked bf16 transposed [16][1024][512] -------
__global__ __launch_bounds__(256) void hpadT_kernel(
    const float* __restrict__ hpad, const int* __restrict__ hlen, u16* __restrict__ dst){
  __shared__ float tile[32][33];
  const int e0 = blockIdx.x*32, t0 = blockIdx.y*32, b = blockIdx.z;
  const int tx = threadIdx.x & 31, ty = threadIdx.x >> 5;
  const int len = hlen[b];
  #pragma unroll
  for (int k = 0; k < 4; ++k){
    int r = ty + k*8;
    tile[r][tx] = hpad[((size_t)b*512 + t0 + r)*1024 + e0 + tx];
  }
  __syncthreads();
  #pragma unroll
  for (int k = 0; k < 4; ++k){
    int el = ty + k*8;
    float m = (t0 + tx < len) ? 1.0f : 0.0f;
    dst[((size_t)b*1024 + e0 + el)*512 + t0 + tx] = f2b(tile[tx][el]*m);
  }
}

// ---------------- bias1 = bih1 + bhh1 ----------------
__global__ void bias_add_kernel(const float* __restrict__ a, const float* __restrict__ b,
                                float* __restrict__ o){
  int i = blockIdx.x*256 + threadIdx.x;
  if (i < 4096) o[i] = a[i] + b[i];
}

// ---------------- eys = bf16(embed[ys_in]) [2176][1024] (rows >= 2064 zeroed) --------------
__global__ __launch_bounds__(256) void eys_kernel(
    const int* __restrict__ ys, const float* __restrict__ embed, u16* __restrict__ eys){
  int row = blockIdx.x;
  int c = threadIdx.x*4;
  if (row < NROWS){
    int b = row / NOL, l = row - b*NOL;
    int tok = (l==0) ? TOK_SOS : ys[b*NL + l - 1];
    float4 v = *(const float4*)(embed + (size_t)tok*1024 + c);
    u16x4 o = { f2b(v.x), f2b(v.y), f2b(v.z), f2b(v.w) };
    *(u16x4*)(eys + (size_t)row*1024 + c) = o;
  } else {
    u16x4 o = {0,0,0,0};
    *(u16x4*)(eys + (size_t)row*1024 + c) = o;
  }
}

// ---------------- generic 128x128 bf16 MFMA tile body ----------------
#define GEMM128_BODY(Aptr, Bptr) \
  const int tid = threadIdx.x, lane = tid & 63, wv = tid >> 6; \
  const int r = lane & 15, q = lane >> 4; \
  const int m0 = blockIdx.x*128, n0 = blockIdx.y*128; \
  const int ar0 = m0 + wv*32 + r; \
  f32x4 acc[2][8]; \
  _Pragma("unroll") \
  for (int a = 0; a < 2; ++a) \
    _Pragma("unroll") \
    for (int s = 0; s < 8; ++s) acc[a][s] = (f32x4){0.f,0.f,0.f,0.f}; \
  const u16* a0p = (Aptr) + (size_t)ar0*1024 + q*8; \
  const u16* a1p = a0p + 16*1024; \
  const u16* bp  = (Bptr) + (size_t)(n0 + r)*1024 + q*8; \
  for (int kt = 0; kt < 32; ++kt){ \
    bf16x8 av0 = *(const bf16x8*)(a0p + kt*32); \
    bf16x8 av1 = *(const bf16x8*)(a1p + kt*32); \
    _Pragma("unroll") \
    for (int s = 0; s < 8; ++s){ \
      bf16x8 bv = *(const bf16x8*)(bp + (size_t)s*16384 + kt*32); \
      acc[0][s] = __builtin_amdgcn_mfma_f32_16x16x32_bf16(av0, bv, acc[0][s], 0,0,0); \
      acc[1][s] = __builtin_amdgcn_mfma_f32_16x16x32_bf16(av1, bv, acc[1][s], 0,0,0); \
    } \
  }

__global__ __launch_bounds__(256) void preenc_g(
    const u16* __restrict__ hpadbf, const u16* __restrict__ wencT, u16* __restrict__ pre){
  GEMM128_BODY(hpadbf, wencT)
  #pragma unroll
  for (int a = 0; a < 2; ++a)
    #pragma unroll
    for (int s = 0; s < 8; ++s)
      #pragma unroll
      for (int rr = 0; rr < 4; ++rr){
        int row = m0 + wv*32 + a*16 + q*4 + rr, col = n0 + s*16 + r;
        pre[(size_t)row*1024 + col] = f2b(tanhf(acc[a][s][rr]));
      }
}

__global__ __launch_bounds__(256) void gey_g(
    const u16* __restrict__ eys, const u16* __restrict__ w0e,
    const float* __restrict__ bih0, const float* __restrict__ bhh0, u16* __restrict__ gey){
  GEMM128_BODY(eys, w0e)
  #pragma unroll
  for (int a = 0; a < 2; ++a)
    #pragma unroll
    for (int s = 0; s < 8; ++s)
      #pragma unroll
      for (int rr = 0; rr < 4; ++rr){
        int row = m0 + wv*32 + a*16 + q*4 + rr, col = n0 + s*16 + r;
        if (row < NROWS)
          gey[(size_t)row*4096 + col] = f2b(acc[a][s][rr] + bih0[col] + bhh0[col]);
      }
}

__global__ __launch_bounds__(256) void logits_g(
    const u16* __restrict__ zallb, const u16* __restrict__ woutT,
    const float* __restrict__ bout, u16* __restrict__ logits){
  GEMM128_BODY(zallb, woutT)
  #pragma unroll
  for (int a = 0; a < 2; ++a)
    #pragma unroll
    for (int s = 0; s < 8; ++s)
      #pragma unroll
      for (int rr = 0; rr < 4; ++rr){
        int row = m0 + wv*32 + a*16 + q*4 + rr, col = n0 + s*16 + r;
        if (row < NROWS && col < NO)
          logits[(size_t)row*NO + col] = f2b(acc[a][s][rr] + bout[col]);
      }
}

// ---------------- grid barrier (round-5 flag/broadcast; 1 poller/WG) ----------------
__device__ __forceinline__ void gbar(u32* af, int epoch){
  __syncthreads();
  if (blockIdx.x == 0){
    int w = threadIdx.x;
    if (w > 0){
      while (coh_ldu(&af[w << 5]) < (u32)epoch) __builtin_amdgcn_s_sleep(1);
    }
    __syncthreads();
    if (threadIdx.x == 0) coh_stu(&af[0], (u32)epoch);
  } else {
    if (threadIdx.x == 0){
      coh_stu(&af[blockIdx.x << 5], (u32)epoch);
      while (coh_ldu(&af[0]) < (u32)epoch) __builtin_amdgcn_s_sleep(1);
    }
    __syncthreads();
  }
}

// ---------------- 16-WG group barrier (one hop: store + 16 parallel polls) ----------------
__device__ __forceinline__ void group_bar(u32* gfl, int epoch){
  __syncthreads();
  if (threadIdx.x == 0) coh_stu(&gfl[blockIdx.x << 5], (u32)epoch);
  const int base = blockIdx.x & ~15;
  if ((int)threadIdx.x < 16){
    while ((int)coh_ldu(&gfl[(base + threadIdx.x) << 5]) < epoch) __builtin_amdgcn_s_sleep(1);
  }
  __syncthreads();
}

// one 16x16 output tile, K=512 slice per wave; weights from LDS, A cached from ring
__device__ __forceinline__ f32x4 tile_gemm(const u16* lw, const u16* ab){
  f32x4 acc = {0.f,0.f,0.f,0.f};
  #pragma unroll
  for (int kt = 0; kt < 16; ++kt){
    bf16x8 a = *(const bf16x8*)(ab + kt*32);
    bf16x8 b = *(const bf16x8*)(lw + kt*512);
    acc = __builtin_amdgcn_mfma_f32_16x16x32_bf16(a, b, acc, 0, 0, 0);
  }
  return acc;
}

// ---------------- persistent sequential kernel: rings + L2-broadcast reads (r15) -----------
__global__ __launch_bounds__(256, 1) void seq_kernel(
    const u16* __restrict__ pre,    // [8192][1024] bf16 (cached)
    const u16* __restrict__ hpadT,  // [16][1024][512] bf16 masked (cached)
    const u16* __restrict__ w0c, const u16* __restrict__ wh0,
    const u16* __restrict__ w1c, const u16* __restrict__ wh1,
    const u16* __restrict__ wdecT,  // [1024 n][1024 k] bf16 (cached)
    const u16* __restrict__ gey,    // [2064][4096] bf16 (cached)
    const float* __restrict__ bias1,// [4096]
    const int* __restrict__ hlen,
    u16* dqr,                       // ring [129][16][1024] bf16
    float* escr,                    // ring [129][16][512] f32
    u16* attcr,                     // ring [129][16][1024] bf16
    u16* z0r,                       // ring [130][16][1024] bf16 (slot0 zeroed)
    u16* z1r,                       // ring [130][16][1024] bf16 (slot0 zeroed)
    u16* zallb,                     // [2176][1024] bf16 (normal stores)
    u32* af, u32* gfl)
{
  __builtin_amdgcn_fence(__ATOMIC_ACQUIRE, "agent");

  const int wg = blockIdx.x, tid = threadIdx.x;
  const int lane = tid & 63, wv = tid >> 6;
  const int r = lane & 15, q = lane >> 4;

  extern __shared__ __align__(16) u16 dynlds[];
  u16* lw1 = dynlds;            // 64 KB (layer1 gates)
  u16* lw0 = dynlds + 32768;    // 64 KB (layer0 gates)
  __shared__ float sred8[8];
  __shared__ float sw[512];
  __shared__ float spart[4][64];
  __shared__ float gex[4][16][16];
  __shared__ float sdq[16*16*4];

  const int dg16 = (wg & 63)*16, sub4 = (wg >> 6)*4;

  #pragma unroll
  for (int it = 0; it < 16; ++it){
    int m = tid + it*256;
    int kb = m >> 4, c = m & 15;
    int k0 = kb*8;
    int gi = c >> 2;
    int d  = dg16 + sub4 + (c & 3);
    size_t gr = (size_t)(gi*1024 + d)*1024;
    const u16* s1 = (k0 < 1024) ? (w1c + gr + k0) : (wh1 + gr + k0 - 1024);
    const u16* s0 = (k0 < 1024) ? (w0c + gr + k0) : (wh0 + gr + k0 - 1024);
    *(u16x8*)(lw1 + (m << 3)) = *(const u16x8*)s1;
    *(u16x8*)(lw0 + (m << 3)) = *(const u16x8*)s0;
  }
  __syncthreads();

  float c0r = 0.f, c1r = 0.f;
  int epoch = 1;
  const int lwoff = ((wv*64 + q)*16 + r) << 3;

  for (int t = 0; t <= NOL; ++t){
    const u16* z0t = z0r + (size_t)t*16384;
    u16* dq_t   = dqr   + (size_t)t*16384;
    float* esc_t= escr  + (size_t)t*8192;
    u16* attc_t = attcr + (size_t)t*16384;

    // ======== Phase A: gemm1+cell1(t-1), dq(t) ========
    if (t >= 1){
      const int s = t - 1;
      const u16* z1p = z1r + (size_t)(t-1)*16384;
      const u16* ab = ((wv < 2) ? z0t : z1p) + r*1024 + (wv & 1)*512 + q*8;
      f32x4 acc = tile_gemm(lw1 + lwoff, ab);
      #pragma unroll
      for (int rr = 0; rr < 4; ++rr) gex[wv][q*4+rr][r] = acc[rr];
      __syncthreads();
      if (tid < 64){
        int b = tid >> 2, dd = tid & 3, d = dg16 + sub4 + dd;
        float g0 = gex[0][b][0*4+dd] + gex[1][b][0*4+dd] + gex[2][b][0*4+dd] + gex[3][b][0*4+dd];
        float g1 = gex[0][b][1*4+dd] + gex[1][b][1*4+dd] + gex[2][b][1*4+dd] + gex[3][b][1*4+dd];
        float g2 = gex[0][b][2*4+dd] + gex[1][b][2*4+dd] + gex[2][b][2*4+dd] + gex[3][b][2*4+dd];
        float g3 = gex[0][b][3*4+dd] + gex[1][b][3*4+dd] + gex[2][b][3*4+dd] + gex[3][b][3*4+dd];
        g0 += bias1[d]; g1 += bias1[1024+d]; g2 += bias1[2048+d]; g3 += bias1[3072+d];
        float cn = sigf(g1)*c1r + sigf(g0)*tanhf(g2);
        float zn = sigf(g3)*tanhf(cn);
        c1r = cn;
        float zn2 = __shfl_down(zn, 1);
        if ((tid & 1) == 0){
          u32 pk = (u32)f2b(zn) | ((u32)f2b(zn2) << 16);
          *(u32*)(zallb + ((size_t)b*NOL + s)*1024 + d) = pk;
          coh_stu((u32*)(z1r + (size_t)t*16384 + b*1024 + d), pk);
        }
      }
      __syncthreads();
    }
    if (t < NOL){
      const int b = tid & 15, ks = tid >> 4;
      float a4[4] = {0.f,0.f,0.f,0.f};
      #pragma unroll
      for (int i = 0; i < 8; ++i){
        bf16x8 za = *(const bf16x8*)(z0t + b*1024 + ks*64 + i*8);
        #pragma unroll
        for (int nn = 0; nn < 4; ++nn){
          bf16x8 wb = *(const bf16x8*)(wdecT + (size_t)(wg*4+nn)*1024 + ks*64 + i*8);
          a4[nn] += dot8(za, wb);
        }
      }
      #pragma unroll
      for (int nn = 0; nn < 4; ++nn) sdq[(ks*16 + b)*4 + nn] = a4[nn];
      __syncthreads();
      if (tid < 64){
        int b2 = tid >> 2, nn = tid & 3;
        float s2 = 0.f;
        #pragma unroll
        for (int ks2 = 0; ks2 < 16; ++ks2) s2 += sdq[(ks2*16 + b2)*4 + nn];
        float dv = tanhf(s2);
        float dv2 = __shfl_down(dv, 1);
        if ((tid & 1) == 0){
          u32 pk = (u32)f2b(dv) | ((u32)f2b(dv2) << 16);
          coh_stu((u32*)(dq_t + b2*1024 + wg*4 + nn), pk);
        }
      }
    }
    gbar(af, epoch++);
    if (t == NOL) break;

    // ======== Phase B: escore = 2 * pre . dq  (32 rows per WG) ========
    {
      const int rbase = wg*32 + wv*8;
      const int b = (wg*32) >> 9;
      const u16* dqb = dq_t + b*1024 + lane*16;
      u16x8 d0 = *(const u16x8*)(dqb);
      u16x8 d1 = *(const u16x8*)(dqb + 8);
      float qv[16];
      #pragma unroll
      for (int j = 0; j < 8; ++j){ qv[j] = b2f(d0[j]); qv[8+j] = b2f(d1[j]); }
      #pragma unroll
      for (int rr = 0; rr < 8; ++rr){
        const u16* pr = pre + (size_t)(rbase+rr)*1024 + lane*16;
        u16x8 p0 = *(const u16x8*)(pr);
        u16x8 p1 = *(const u16x8*)(pr+8);
        float acc = 0.f;
        #pragma unroll
        for (int j = 0; j < 8; ++j){
          acc += b2f(p0[j])*qv[j];
          acc += b2f(p1[j])*qv[8+j];
        }
        #pragma unroll
        for (int off = 32; off > 0; off >>= 1) acc += __shfl_xor(acc, off, 64);
        if (lane == 0) coh_stf(&esc_t[rbase+rr], 2.0f*acc);
      }
    }
    group_bar(gfl, epoch++);

    // ======== Phase C: softmax + att_c (b = wg>>4, 64-col e-slice; wave reductions) =======
    {
      const int b = wg >> 4, ec = wg & 15;
      const int len = hlen[b];
      float e0 = (tid < len)     ? esc_t[b*512 + tid]       : -INFINITY;
      float e1 = (tid+256 < len) ? esc_t[b*512 + tid + 256] : -INFINITY;
      float mloc = fmaxf(e0, e1);
      #pragma unroll
      for (int off = 32; off > 0; off >>= 1) mloc = fmaxf(mloc, __shfl_xor(mloc, off, 64));
      if (lane == 0) sred8[wv] = mloc;
      __syncthreads();
      float mx = fmaxf(fmaxf(sred8[0], sred8[1]), fmaxf(sred8[2], sred8[3]));
      float p0 = (tid < len)     ? expf(e0 - mx) : 0.0f;
      float p1 = (tid+256 < len) ? expf(e1 - mx) : 0.0f;
      float sloc = p0 + p1;
      #pragma unroll
      for (int off = 32; off > 0; off >>= 1) sloc += __shfl_xor(sloc, off, 64);
      if (lane == 0) sred8[4 + wv] = sloc;
      __syncthreads();
      float inv = 1.0f/(sred8[4] + sred8[5] + sred8[6] + sred8[7]);
      sw[tid] = p0*inv; sw[tid+256] = p1*inv;
      __syncthreads();
      const int el = tid & 63, th = tid >> 6;
      const u16* hp = hpadT + ((size_t)b*1024 + ec*64 + el)*512 + th*128;
      float acc = 0.f;
      #pragma unroll
      for (int i = 0; i < 16; ++i){
        u16x8 v = *(const u16x8*)(hp + i*8);
        #pragma unroll
        for (int j = 0; j < 8; ++j) acc += sw[th*128 + i*8 + j]*b2f(v[j]);
      }
      spart[th][el] = acc;
      __syncthreads();
      if (tid < 64){
        float s2 = spart[0][tid]+spart[1][tid]+spart[2][tid]+spart[3][tid];
        float s2n = __shfl_down(s2, 1);
        if ((tid & 1) == 0){
          u32 pk = (u32)f2b(s2) | ((u32)f2b(s2n) << 16);
          coh_stu((u32*)(attc_t + b*1024 + ec*64 + tid), pk);
        }
      }
    }
    gbar(af, epoch++);

    // ======== Phase D: gemm0 + cell0(t) -> z0 ring slot t+1 ========
    {
      const u16* ab = ((wv < 2) ? attc_t : z0t) + r*1024 + (wv & 1)*512 + q*8;
      f32x4 acc = tile_gemm(lw0 + lwoff, ab);
      #pragma unroll
      for (int rr = 0; rr < 4; ++rr) gex[wv][q*4+rr][r] = acc[rr];
      __syncthreads();
      if (tid < 64){
        int b = tid >> 2, dd = tid & 3, d = dg16 + sub4 + dd;
        const u16* gr = gey + ((size_t)b*NOL + t)*4096 + d;
        float g0 = gex[0][b][0*4+dd] + gex[1][b][0*4+dd] + gex[2][b][0*4+dd] + gex[3][b][0*4+dd];
        float g1 = gex[0][b][1*4+dd] + gex[1][b][1*4+dd] + gex[2][b][1*4+dd] + gex[3][b][1*4+dd];
        float g2 = gex[0][b][2*4+dd] + gex[1][b][2*4+dd] + gex[2][b][2*4+dd] + gex[3][b][2*4+dd];
        float g3 = gex[0][b][3*4+dd] + gex[1][b][3*4+dd] + gex[2][b][3*4+dd] + gex[3][b][3*4+dd];
        g0 += b2f(gr[0]); g1 += b2f(gr[1024]); g2 += b2f(gr[2048]); g3 += b2f(gr[3072]);
        float cn = sigf(g1)*c0r + sigf(g0)*tanhf(g2);
        float zn = sigf(g3)*tanhf(cn);
        c0r = cn;
        float zn2 = __shfl_down(zn, 1);
        if ((tid & 1) == 0){
          u32 pk = (u32)f2b(zn) | ((u32)f2b(zn2) << 16);
          coh_stu((u32*)(z0r + (size_t)(t+1)*16384 + b*1024 + d), pk);
        }
      }
    }
    gbar(af, epoch++);
  }
}

// ---------------- per-row single-pass online log_softmax + NLL + argmax ----------------
__global__ __launch_bounds__(256) void loss_kernel(
    const u16* __restrict__ logits, const int* __restrict__ ys, float* __restrict__ accum){
  int row = blockIdx.x;
  int tid = threadIdx.x;
  const u16* lr = logits + (size_t)row * NO;
  __shared__ float sm[256], ss[256];
  __shared__ int   si[256];
  float m = -INFINITY, s = 0.f; int mi = 0x7FFFFFFF;
  for (int n = tid; n < NO; n += 256){
    float v = b2f(lr[n]);
    if (v > m){
      s = s*__expf(m - v) + 1.0f;
      m = v; mi = n;
    } else {
      s += __expf(v - m);
    }
  }
  sm[tid] = m; ss[tid] = s; si[tid] = mi;
  __syncthreads();
  for (int st = 128; st > 0; st >>= 1){
    if (tid < st){
      float m1 = sm[tid], s1 = ss[tid]; int i1 = si[tid];
      float m2 = sm[tid+st], s2 = ss[tid+st]; int i2 = si[tid+st];
      float M = fmaxf(m1, m2);
      ss[tid] = s1*__expf(m1 - M) + s2*__expf(m2 - M);
      sm[tid] = M;
      si[tid] = (m1 > m2) ? i1 : (m2 > m1) ? i2 : min(i1, i2);
    }
    __syncthreads();
  }
  if (tid == 0){
    int b = row / NOL, l = row - b*NOL;
    int label = (l < NL) ? ys[b*NL + l] : TOK_EOS;
    float lse = sm[0] + logf(ss[0]);
    float nll = lse - b2f(lr[label]);
    atomicAdd(&accum[0], nll);
    atomicAdd(&accum[1], (si[0]==label) ? 1.0f : 0.0f);
  }
}

__global__ void finalize_kernel(const float* __restrict__ accum, float* __restrict__ out){
  out[0] = accum[0] / (float)NROWS * (float)(NOL-1);
  out[1] = accum[1] / (float)NROWS;
}

extern "C" void kernel_launch(void* const* d_in, const int* in_sizes, int n_in,
                              void* d_out, int out_size, void* d_ws, size_t ws_size,
                              hipStream_t stream){
  const float* hpad  = (const float*)d_in[0];
  const int*   hlen  = (const int*)  d_in[1];
  const int*   ys    = (const int*)  d_in[2];
  const float* embed = (const float*)d_in[3];
  const float* Wenc  = (const float*)d_in[4];
  const float* Wdec  = (const float*)d_in[5];
  const float* Wih0  = (const float*)d_in[6];
  const float* Whh0  = (const float*)d_in[7];
  const float* bih0  = (const float*)d_in[8];
  const float* bhh0  = (const float*)d_in[9];
  const float* Wih1  = (const float*)d_in[10];
  const float* Whh1  = (const float*)d_in[11];
  const float* bih1  = (const float*)d_in[12];
  const float* bhh1  = (const float*)d_in[13];
  const float* Wout  = (const float*)d_in[14];
  const float* bout  = (const float*)d_in[15];
  float* out = (float*)d_out;

  char* ws = (char*)d_ws;
  size_t cur = 0;
  auto alloc = [&](size_t bytes) -> char* {
    char* p = ws + cur;
    cur += (bytes + 255) & ~(size_t)255;
    return p;
  };
  u16*   pre_bf   = (u16*)  alloc(16777216);   // [8192][1024]
  u16*   hpadT    = (u16*)  alloc(16777216);   // [16][1024][512]
  u16*   w0c      = (u16*)  alloc(8388608);    // Wih0[:,1024:]
  u16*   wh0      = (u16*)  alloc(8388608);
  u16*   w1c      = (u16*)  alloc(8388608);
  u16*   wh1      = (u16*)  alloc(8388608);
  u16*   wdecT    = (u16*)  alloc(2097152);    // [1024][1024]
  u16*   wencT    = (u16*)  alloc(2097152);    // [1024][1024]
  u16*   woutT    = (u16*)  alloc(20709376);   // [10112][1024]
  u16*   gey      = (u16*)  alloc(16908288);   // [2064][4096]
  u16*   zallb    = (u16*)  alloc(4456448);    // [2176][1024]
  u16*   logits   = (u16*)  alloc(41280000);   // [2064][10000]
  float* bias1    = (float*)alloc(16384);
  // ---- write-once rings ----
  u16*   dqr      = (u16*)  alloc(129u*32768);
  float* escr     = (float*)alloc(129u*32768);
  u16*   attcr    = (u16*)  alloc(129u*32768);
  u16*   z0r      = (u16*)  alloc(130u*32768);
  u16*   z1r      = (u16*)  alloc(130u*32768);
  // ---- zeroed each launch ----
  u32*   af       = (u32*)  alloc(32768);
  u32*   gfl      = (u32*)  alloc(32768);
  float* accum    = (float*)alloc(128);

  // pre-seq staging buffers ALIAS the logits region (dead until logits_g)
  u16*   hpad_bf  = (u16*)logits;              // 16 MB
  u16*   eys      = (u16*)(logits + 8388608);
  u16*   w0e      = (u16*)(logits + 11165696);

  zero4_kernel<<<17, 256, 0, stream>>>((uint4*)af, 4104);
  zero4_kernel<<<8, 256, 0, stream>>>((uint4*)z0r, 2048);
  zero4_kernel<<<8, 256, 0, stream>>>((uint4*)z1r, 2048);

  tcvt_kernel<<<dim3(32,32),  256, 0, stream>>>(Wenc, 1024, 1024, wencT);
  tcvt_kernel<<<dim3(32,32),  256, 0, stream>>>(Wdec, 1024, 1024, wdecT);
  tcvt_kernel<<<dim3(316,32), 256, 0, stream>>>(Wout, 1024, NO,   woutT);
  cvt5_kernel<<<dim3(4096,5), 256, 0, stream>>>(Wih0, Whh0, Wih1, Whh1,
                                                w0c, wh0, w1c, wh1, w0e);
  hpadbf_kernel<<<8192, 256, 0, stream>>>(hpad, hlen, hpad_bf);
  hpadT_kernel<<<dim3(32,16,16), 256, 0, stream>>>(hpad, hlen, hpadT);
  bias_add_kernel<<<16, 256, 0, stream>>>(bih1, bhh1, bias1);
  eys_kernel<<<2176, 256, 0, stream>>>(ys, embed, eys);

  preenc_g<<<dim3(64, 8),  256, 0, stream>>>(hpad_bf, wencT, pre_bf);
  gey_g   <<<dim3(17, 32), 256, 0, stream>>>(eys, w0e, bih0, bhh0, gey);

  hipFuncSetAttribute((const void*)seq_kernel,
                      hipFuncAttributeMaxDynamicSharedMemorySize, 131072);
  seq_kernel<<<NBLK, 256, 131072, stream>>>(pre_bf, hpadT, w0c, wh0, w1c, wh1,
                                            wdecT, gey, bias1, hlen,
                                            dqr, escr, attcr, z0r, z1r, zallb, af, gfl);

  logits_g<<<dim3(17, 79), 256, 0, stream>>>(zallb, woutT, bout, logits);
  loss_kernel<<<NROWS, 256, 0, stream>>>(logits, ys, accum);
  finalize_kernel<<<1, 1, 0, stream>>>(accum, out);
}